// Round 2
// baseline (5231.672 us; speedup 1.0000x reference)
//
#include <hip/hip_runtime.h>
#include <hip/hip_bf16.h>

#define NN 131072
#define EE 1048576
#define IN_F 74
#define HH 128
#define LL 3

// ============ init: h = nf @ W_init ([N x 74] @ [74 x 128]) ============
__global__ __launch_bounds__(256) void k_init_gemm(
    const float* __restrict__ nf, const float* __restrict__ Wi,
    float* __restrict__ h, int n)
{
    int node = blockIdx.x * 2 + (threadIdx.x >> 7);
    int c = threadIdx.x & 127;
    if (node >= n) return;
    const float* row = nf + (long)node * IN_F;
    float s = 0.f;
#pragma unroll
    for (int k = 0; k < IN_F; ++k)
        s += row[k] * Wi[k * HH + c];
    h[(long)node * HH + c] = s;
}

// ============ CSR build ============
__global__ __launch_bounds__(256) void k_hist(const int* __restrict__ dst, int* __restrict__ deg)
{
    int e = blockIdx.x * 256 + threadIdx.x;
    atomicAdd(&deg[dst[e]], 1);
}

__global__ __launch_bounds__(256) void k_scan1(const int* __restrict__ deg, int* __restrict__ bsum)
{
    __shared__ int s[256];
    int b = blockIdx.x, t = threadIdx.x;
    int v = 0;
#pragma unroll
    for (int i = 0; i < 4; ++i) v += deg[b * 1024 + t * 4 + i];
    s[t] = v;
    __syncthreads();
    for (int st = 128; st > 0; st >>= 1) {
        if (t < st) s[t] += s[t + st];
        __syncthreads();
    }
    if (t == 0) bsum[b] = s[0];
}

__global__ void k_scan2(int* __restrict__ bsum, int nb)
{
    if (threadIdx.x == 0) {
        int run = 0;
        for (int i = 0; i < nb; ++i) { int v = bsum[i]; bsum[i] = run; run += v; }
    }
}

__global__ __launch_bounds__(256) void k_scan3(
    const int* __restrict__ deg, const int* __restrict__ bsum, int* __restrict__ row_start)
{
    __shared__ int s[256];
    int b = blockIdx.x, t = threadIdx.x;
    int base = b * 1024 + t * 4;
    int d0 = deg[base], d1 = deg[base + 1], d2 = deg[base + 2], d3 = deg[base + 3];
    int local = d0 + d1 + d2 + d3;
    s[t] = local;
    __syncthreads();
    for (int st = 1; st < 256; st <<= 1) {
        int v = (t >= st) ? s[t - st] : 0;
        __syncthreads();
        s[t] += v;
        __syncthreads();
    }
    int excl = s[t] - local + bsum[b];
    row_start[base] = excl;
    row_start[base + 1] = excl + d0;
    row_start[base + 2] = excl + d0 + d1;
    row_start[base + 3] = excl + d0 + d1 + d2;
    if (b == gridDim.x - 1 && t == 255) row_start[NN] = excl + local;
}

__global__ __launch_bounds__(256) void k_fill(
    const int* __restrict__ src, const int* __restrict__ dst,
    const int* __restrict__ row_start, int* __restrict__ cursor, int* __restrict__ csr_src)
{
    int e = blockIdx.x * 256 + threadIdx.x;
    int d = dst[e];
    int pos = atomicAdd(&cursor[d], 1);
    csr_src[row_start[d] + pos] = src[e];
}

// ============ fused layer ============
__device__ __forceinline__ float sigmoidf_(float x) { return 1.f / (1.f + __expf(-x)); }
__device__ __forceinline__ float tanhf_(float x)
{
    x = fminf(fmaxf(x, -15.f), 15.f);
    float e2 = __expf(2.f * x);
    return (e2 - 1.f) / (e2 + 1.f);
}

// acc[i][j] += sum_k As[k][tm0+i] * W[o][k], o = tn0+j (W row-major [128 out][128 k])
__device__ __forceinline__ void gemm_acc(
    float (&acc)[8][4], const float (*As)[68], const float* __restrict__ W,
    float (*Ws)[132], int t, int tm0, int tn0)
{
    for (int k0 = 0; k0 < 128; k0 += 16) {
        __syncthreads();
#pragma unroll
        for (int p = 0; p < 2; ++p) {
            int idx = p * 256 + t;
            int o = idx >> 2;
            int c4 = idx & 3;
            float4 v = *reinterpret_cast<const float4*>(&W[(long)o * 128 + k0 + c4 * 4]);
            Ws[c4 * 4 + 0][o] = v.x;
            Ws[c4 * 4 + 1][o] = v.y;
            Ws[c4 * 4 + 2][o] = v.z;
            Ws[c4 * 4 + 3][o] = v.w;
        }
        __syncthreads();
#pragma unroll
        for (int k = 0; k < 16; ++k) {
            float4 a0 = *reinterpret_cast<const float4*>(&As[k0 + k][tm0]);
            float4 a1 = *reinterpret_cast<const float4*>(&As[k0 + k][tm0 + 4]);
            float4 b = *reinterpret_cast<const float4*>(&Ws[k][tn0]);
            float a[8] = {a0.x, a0.y, a0.z, a0.w, a1.x, a1.y, a1.z, a1.w};
            float bb[4] = {b.x, b.y, b.z, b.w};
#pragma unroll
            for (int i = 0; i < 8; ++i)
#pragma unroll
                for (int j = 0; j < 4; ++j)
                    acc[i][j] += a[i] * bb[j];
        }
    }
}

#define ZERO84(A) do { _Pragma("unroll") for (int i_ = 0; i_ < 8; ++i_) _Pragma("unroll") for (int j_ = 0; j_ < 4; ++j_) (A)[i_][j_] = 0.f; } while (0)

__global__ __launch_bounds__(256) void k_layer(
    const float* __restrict__ h_in, float* __restrict__ h_out,
    const int* __restrict__ row_start, const int* __restrict__ csr_src,
    const float* __restrict__ lW, const float* __restrict__ lb,
    const float* __restrict__ Wih, const float* __restrict__ Whh,
    const float* __restrict__ bi, const float* __restrict__ bh)
{
    __shared__ float xa_s[128][68];  // agg tile, then x tile (transposed [col][node])
    __shared__ float h_s[128][68];   // own h tile (transposed)
    __shared__ float Ws[16][132];    // weight staging [k][out]

    int n0 = blockIdx.x * 64;
    int t = threadIdx.x;
    int col = t & 127;
    int nl0 = t >> 7;

    // P0+P1: load own h tile + gather neighbor sums (CSR)
    for (int nl = nl0; nl < 64; nl += 2) {
        int node = n0 + nl;
        h_s[col][nl] = h_in[(long)node * HH + col];
        int e0 = row_start[node];
        int e1 = row_start[node + 1];
        float acc = 0.f;
        for (int e = e0; e < e1; ++e)
            acc += h_in[(long)csr_src[e] * HH + col];
        xa_s[col][nl] = acc;
    }
    __syncthreads();

    int tm0 = (t & 7) * 8;   // 8 nodes
    int tn0 = (t >> 3) * 4;  // 4 out cols

    // x = relu(agg @ lW^T + lb), written back into xa_s
    {
        float acc[8][4];
        ZERO84(acc);
        gemm_acc(acc, xa_s, lW, Ws, t, tm0, tn0);
        __syncthreads();  // all agg reads done before overwrite
#pragma unroll
        for (int i = 0; i < 8; ++i)
#pragma unroll
            for (int j = 0; j < 4; ++j)
                xa_s[tn0 + j][tm0 + i] = fmaxf(acc[i][j] + lb[tn0 + j], 0.f);
        // next gemm_acc's leading __syncthreads() publishes these writes
    }

    // r = sigmoid(x@Wih_r + h@Whh_r + bi_r + bh_r)
    float r[8][4];
    ZERO84(r);
    gemm_acc(r, xa_s, Wih, Ws, t, tm0, tn0);
    gemm_acc(r, h_s, Whh, Ws, t, tm0, tn0);
#pragma unroll
    for (int i = 0; i < 8; ++i)
#pragma unroll
        for (int j = 0; j < 4; ++j)
            r[i][j] = sigmoidf_(r[i][j] + bi[tn0 + j] + bh[tn0 + j]);

    // h_n (raw) = h@Whh_n
    float nh[8][4];
    ZERO84(nh);
    gemm_acc(nh, h_s, Whh + 256 * 128, Ws, t, tm0, tn0);

    // i_n = x@Wih_n; n = tanh(i_n + bi_n + r*(h_n + bh_n))  (n stored into r)
    {
        float ni[8][4];
        ZERO84(ni);
        gemm_acc(ni, xa_s, Wih + 256 * 128, Ws, t, tm0, tn0);
#pragma unroll
        for (int i = 0; i < 8; ++i)
#pragma unroll
            for (int j = 0; j < 4; ++j)
                r[i][j] = tanhf_(ni[i][j] + bi[256 + tn0 + j] +
                                 r[i][j] * (nh[i][j] + bh[256 + tn0 + j]));
    }

    // z = sigmoid(x@Wih_z + h@Whh_z + bi_z + bh_z)
    float z[8][4];
    ZERO84(z);
    gemm_acc(z, xa_s, Wih + 128 * 128, Ws, t, tm0, tn0);
    gemm_acc(z, h_s, Whh + 128 * 128, Ws, t, tm0, tn0);

    // h' = (1-z)*n + z*h_old ; coalesced float4 store
#pragma unroll
    for (int i = 0; i < 8; ++i) {
        float4 o4;
        float* o = &o4.x;
#pragma unroll
        for (int j = 0; j < 4; ++j) {
            float zv = sigmoidf_(z[i][j] + bi[128 + tn0 + j] + bh[128 + tn0 + j]);
            float hv = h_s[tn0 + j][tm0 + i];
            o[j] = (1.f - zv) * r[i][j] + zv * hv;
        }
        *reinterpret_cast<float4*>(&h_out[(long)(n0 + tm0 + i) * HH + tn0]) = o4;
    }
}

extern "C" void kernel_launch(void* const* d_in, const int* in_sizes, int n_in,
                              void* d_out, int out_size, void* d_ws, size_t ws_size,
                              hipStream_t stream)
{
    const float* nf     = (const float*)d_in[0];  // [N][74]
    const int*   src    = (const int*)d_in[1];    // [E]
    const int*   dst    = (const int*)d_in[2];    // [E]
    const float* W_init = (const float*)d_in[3];  // [74][128]
    const float* lin_W  = (const float*)d_in[4];  // [3][128][128]
    const float* lin_b  = (const float*)d_in[5];  // [3][128]
    const float* Wih    = (const float*)d_in[6];  // [3][384][128]
    const float* Whh    = (const float*)d_in[7];  // [3][384][128]
    const float* bih    = (const float*)d_in[8];  // [3][384]
    const float* bhh    = (const float*)d_in[9];  // [3][384]

    char* ws = (char*)d_ws;
    float* hA       = (float*)(ws);                    // 64MB
    int*   row_start = (int*)(ws + (64ull << 20));     // (N+1)*4
    int*   deg      = (int*)(ws + (66ull << 20));      // N*4
    int*   cursor   = (int*)(ws + (68ull << 20));      // N*4
    int*   bsum     = (int*)(ws + (70ull << 20));      // 128*4
    int*   csr_src  = (int*)(ws + (72ull << 20));      // E*4 = 4MB

    // init transform -> hA
    k_init_gemm<<<NN / 2, 256, 0, stream>>>(nf, W_init, hA, NN);

    // CSR build (deterministic per call)
    hipMemsetAsync(deg, 0, (size_t)NN * 4, stream);
    hipMemsetAsync(cursor, 0, (size_t)NN * 4, stream);
    k_hist<<<EE / 256, 256, 0, stream>>>(dst, deg);
    k_scan1<<<NN / 1024, 256, 0, stream>>>(deg, bsum);
    k_scan2<<<1, 64, 0, stream>>>(bsum, NN / 1024);
    k_scan3<<<NN / 1024, 256, 0, stream>>>(deg, bsum, row_start);
    k_fill<<<EE / 256, 256, 0, stream>>>(src, dst, row_start, cursor, csr_src);

    // layers: hA -> d_out -> hA -> d_out
    const float* hin = hA;
    float* hout = (float*)d_out;
    for (int l = 0; l < LL; ++l) {
        k_layer<<<NN / 64, 256, 0, stream>>>(
            hin, hout, row_start, csr_src,
            lin_W + (size_t)l * HH * HH, lin_b + (size_t)l * HH,
            Wih + (size_t)l * 3 * HH * HH, Whh + (size_t)l * 3 * HH * HH,
            bih + (size_t)l * 3 * HH, bhh + (size_t)l * 3 * HH);
        const float* tmp = hout;
        hout = (float*)hin;
        hin = tmp;
    }
}

// Round 3
// 2246.325 us; speedup vs baseline: 2.3290x; 2.3290x over previous
//
#include <hip/hip_runtime.h>
#include <hip/hip_bf16.h>

#define NN 131072
#define EE 1048576
#define IN_F 74
#define HH 128
#define LL 3

using f32x4  = __attribute__((ext_vector_type(4))) float;
using bf16x8 = __attribute__((ext_vector_type(8))) short;

__device__ __forceinline__ short f2bf(float f) {
    __hip_bfloat16 b = __float2bfloat16(f);
    return __builtin_bit_cast(short, b);
}
__device__ __forceinline__ float bf2f(short s) {
    unsigned int u = ((unsigned int)(unsigned short)s) << 16;
    return __builtin_bit_cast(float, u);
}
__device__ __forceinline__ float sigmoidf_(float x) { return 1.f / (1.f + __expf(-x)); }
__device__ __forceinline__ float tanhf_(float x)
{
    x = fminf(fmaxf(x, -15.f), 15.f);
    float e2 = __expf(2.f * x);
    return (e2 - 1.f) / (e2 + 1.f);
}

// ============ init: h = nf @ W_init ([N x 74] @ [74 x 128]) -> f32 ============
__global__ __launch_bounds__(256) void k_init_gemm(
    const float* __restrict__ nf, const float* __restrict__ Wi,
    float* __restrict__ h, int n)
{
    int node = blockIdx.x * 2 + (threadIdx.x >> 7);
    int c = threadIdx.x & 127;
    if (node >= n) return;
    const float* row = nf + (long)node * IN_F;
    float s = 0.f;
#pragma unroll
    for (int k = 0; k < IN_F; ++k)
        s += row[k] * Wi[k * HH + c];
    h[(long)node * HH + c] = s;
}

// ============ CSR build ============
__global__ __launch_bounds__(256) void k_hist(const int* __restrict__ dsti, int* __restrict__ deg)
{
    int e = blockIdx.x * 256 + threadIdx.x;
    atomicAdd(&deg[dsti[e]], 1);
}

__global__ __launch_bounds__(256) void k_scan1(const int* __restrict__ deg, int* __restrict__ bsum)
{
    __shared__ int s[256];
    int b = blockIdx.x, t = threadIdx.x;
    int v = 0;
#pragma unroll
    for (int i = 0; i < 4; ++i) v += deg[b * 1024 + t * 4 + i];
    s[t] = v;
    __syncthreads();
    for (int st = 128; st > 0; st >>= 1) {
        if (t < st) s[t] += s[t + st];
        __syncthreads();
    }
    if (t == 0) bsum[b] = s[0];
}

__global__ void k_scan2(int* __restrict__ bsum, int nb)
{
    if (threadIdx.x == 0) {
        int run = 0;
        for (int i = 0; i < nb; ++i) { int v = bsum[i]; bsum[i] = run; run += v; }
    }
}

__global__ __launch_bounds__(256) void k_scan3(
    const int* __restrict__ deg, const int* __restrict__ bsum, int* __restrict__ row_start)
{
    __shared__ int s[256];
    int b = blockIdx.x, t = threadIdx.x;
    int base = b * 1024 + t * 4;
    int d0 = deg[base], d1 = deg[base + 1], d2 = deg[base + 2], d3 = deg[base + 3];
    int local = d0 + d1 + d2 + d3;
    s[t] = local;
    __syncthreads();
    for (int st = 1; st < 256; st <<= 1) {
        int v = (t >= st) ? s[t - st] : 0;
        __syncthreads();
        s[t] += v;
        __syncthreads();
    }
    int excl = s[t] - local + bsum[b];
    row_start[base] = excl;
    row_start[base + 1] = excl + d0;
    row_start[base + 2] = excl + d0 + d1;
    row_start[base + 3] = excl + d0 + d1 + d2;
    if (b == gridDim.x - 1 && t == 255) row_start[NN] = excl + local;
}

__global__ __launch_bounds__(256) void k_fill(
    const int* __restrict__ src, const int* __restrict__ dsti,
    const int* __restrict__ row_start, int* __restrict__ cursor, int* __restrict__ csr_src)
{
    int e = blockIdx.x * 256 + threadIdx.x;
    int d = dsti[e];
    int pos = atomicAdd(&cursor[d], 1);
    csr_src[row_start[d] + pos] = src[e];
}

// ============ weight split f32 -> (hi, lo) bf16 planes ============
__global__ __launch_bounds__(256) void k_split(
    const float* __restrict__ srcw, unsigned short* __restrict__ hi,
    unsigned short* __restrict__ lo, int n)
{
    int i = blockIdx.x * 256 + threadIdx.x;
    if (i >= n) return;
    float a = srcw[i];
    short h = f2bf(a);
    float rem = a - bf2f(h);
    hi[i] = (unsigned short)h;
    lo[i] = (unsigned short)f2bf(rem);
}

// ============ fused gather + x-GEMM ============
// Block: 32 nodes, 256 threads (4 waves). Gather: wave w -> nodes w*8..w*8+8,
// 64 lanes = 2 col-halves per lane. agg in swizzled LDS (f32). Then MFMA:
// x = relu(agg @ lW^T + lb) via split-bf16, wave = 16 nodes x 64 j.
__global__ __launch_bounds__(256) void k_x(
    const float* __restrict__ h,
    const int* __restrict__ row_start, const int* __restrict__ csr_src,
    const unsigned short* __restrict__ lWhi, const unsigned short* __restrict__ lWlo,
    const float* __restrict__ lb,
    float* __restrict__ xout)
{
    __shared__ float aggs[32 * 128];
    char* abase = (char*)aggs;
    int n0 = blockIdx.x * 32;
    int t = threadIdx.x;
    int w = t >> 6, lane = t & 63;

    // ---- gather phase ----
    for (int i = 0; i < 8; ++i) {
        int nl = w * 8 + i;
        int node = n0 + nl;
        int e0 = row_start[node], e1 = row_start[node + 1];
        float a0 = 0.f, a1 = 0.f;
        for (int e = e0; e < e1; ++e) {
            int s = csr_src[e];
            const float* hr = h + (long)s * HH;
            a0 += hr[lane];
            a1 += hr[64 + lane];
        }
        int swz = (nl & 7) << 4;
        *reinterpret_cast<float*>(abase + (((nl * 512) + lane * 4) ^ swz)) = a0;
        *reinterpret_cast<float*>(abase + (((nl * 512) + 256 + lane * 4) ^ swz)) = a1;
    }
    __syncthreads();

    // ---- GEMM phase ----
    int ng = w >> 1, jg = w & 1;
    int l16 = lane & 15, lq = lane >> 4;

    f32x4 acc[4];
#pragma unroll
    for (int js = 0; js < 4; ++js) acc[js] = (f32x4){0.f, 0.f, 0.f, 0.f};

#pragma unroll
    for (int kk = 0; kk < 4; ++kk) {
        int k0 = kk * 32;
        int nodeL = ng * 16 + l16;
        int kb = (k0 + lq * 8) * 4;
        int swz = (nodeL & 7) << 4;
        float4 f0 = *reinterpret_cast<const float4*>(abase + ((nodeL * 512 + kb) ^ swz));
        float4 f1 = *reinterpret_cast<const float4*>(abase + ((nodeL * 512 + kb + 16) ^ swz));
        float av[8] = {f0.x, f0.y, f0.z, f0.w, f1.x, f1.y, f1.z, f1.w};
        bf16x8 ahi, alo;
#pragma unroll
        for (int e = 0; e < 8; ++e) {
            short hh_ = f2bf(av[e]);
            ahi[e] = hh_;
            alo[e] = f2bf(av[e] - bf2f(hh_));
        }
#pragma unroll
        for (int js = 0; js < 4; ++js) {
            int jrow = jg * 64 + js * 16 + l16;
            bf16x8 Bh = *reinterpret_cast<const bf16x8*>(lWhi + (long)jrow * HH + k0 + lq * 8);
            bf16x8 Bl = *reinterpret_cast<const bf16x8*>(lWlo + (long)jrow * HH + k0 + lq * 8);
            acc[js] = __builtin_amdgcn_mfma_f32_16x16x32_bf16(ahi, Bh, acc[js], 0, 0, 0);
            acc[js] = __builtin_amdgcn_mfma_f32_16x16x32_bf16(ahi, Bl, acc[js], 0, 0, 0);
            acc[js] = __builtin_amdgcn_mfma_f32_16x16x32_bf16(alo, Bh, acc[js], 0, 0, 0);
        }
    }

    // ---- epilogue: relu + bias, f32 store ----
#pragma unroll
    for (int js = 0; js < 4; ++js) {
        int j = jg * 64 + js * 16 + l16;
        float bj = lb[j];
#pragma unroll
        for (int r = 0; r < 4; ++r) {
            int node = n0 + ng * 16 + lq * 4 + r;
            float v = fmaxf(acc[js][r] + bj, 0.f);
            xout[(long)node * HH + j] = v;
        }
    }
}

// ============ fused GRU (gi + gh + gates), LDS-free, barrier-free ============
// Block: 32 nodes, 256 threads (4 waves). Wave = 16 nodes x 64 j.
// All 3 gates accumulated in one K-loop: aI/aH[3][4] (96 VGPR accs).
__global__ __launch_bounds__(256) void k_gru(
    const float* x, const float* hbuf, float* hout,
    const unsigned short* __restrict__ Wihhi, const unsigned short* __restrict__ Wihlo,
    const unsigned short* __restrict__ Whhhi, const unsigned short* __restrict__ Whhlo,
    const float* __restrict__ bi, const float* __restrict__ bh)
{
    int n0 = blockIdx.x * 32;
    int t = threadIdx.x;
    int w = t >> 6, lane = t & 63;
    int ng = w >> 1, jg = w & 1;
    int l16 = lane & 15, lq = lane >> 4;

    f32x4 aI[3][4], aH[3][4];
#pragma unroll
    for (int g = 0; g < 3; ++g)
#pragma unroll
        for (int js = 0; js < 4; ++js) {
            aI[g][js] = (f32x4){0.f, 0.f, 0.f, 0.f};
            aH[g][js] = (f32x4){0.f, 0.f, 0.f, 0.f};
        }

    int nodeA = n0 + ng * 16 + l16;
    const float* xrow = x + (long)nodeA * HH;
    const float* hrow = hbuf + (long)nodeA * HH;

#pragma unroll
    for (int kk = 0; kk < 4; ++kk) {
        int koff = kk * 32 + lq * 8;
        float4 xf0 = *reinterpret_cast<const float4*>(xrow + koff);
        float4 xf1 = *reinterpret_cast<const float4*>(xrow + koff + 4);
        float4 hf0 = *reinterpret_cast<const float4*>(hrow + koff);
        float4 hf1 = *reinterpret_cast<const float4*>(hrow + koff + 4);
        float xv[8] = {xf0.x, xf0.y, xf0.z, xf0.w, xf1.x, xf1.y, xf1.z, xf1.w};
        float hv[8] = {hf0.x, hf0.y, hf0.z, hf0.w, hf1.x, hf1.y, hf1.z, hf1.w};
        bf16x8 xhi, xlo, hhi, hlo;
#pragma unroll
        for (int e = 0; e < 8; ++e) {
            short s1 = f2bf(xv[e]);
            xhi[e] = s1;
            xlo[e] = f2bf(xv[e] - bf2f(s1));
            short s2 = f2bf(hv[e]);
            hhi[e] = s2;
            hlo[e] = f2bf(hv[e] - bf2f(s2));
        }
#pragma unroll
        for (int g = 0; g < 3; ++g) {
#pragma unroll
            for (int js = 0; js < 4; ++js) {
                long wo = (long)(g * 128 + jg * 64 + js * 16 + l16) * HH + koff;
                bf16x8 wih_h = *reinterpret_cast<const bf16x8*>(Wihhi + wo);
                bf16x8 wih_l = *reinterpret_cast<const bf16x8*>(Wihlo + wo);
                bf16x8 whh_h = *reinterpret_cast<const bf16x8*>(Whhhi + wo);
                bf16x8 whh_l = *reinterpret_cast<const bf16x8*>(Whhlo + wo);
                aI[g][js] = __builtin_amdgcn_mfma_f32_16x16x32_bf16(xhi, wih_h, aI[g][js], 0, 0, 0);
                aI[g][js] = __builtin_amdgcn_mfma_f32_16x16x32_bf16(xhi, wih_l, aI[g][js], 0, 0, 0);
                aI[g][js] = __builtin_amdgcn_mfma_f32_16x16x32_bf16(xlo, wih_h, aI[g][js], 0, 0, 0);
                aH[g][js] = __builtin_amdgcn_mfma_f32_16x16x32_bf16(hhi, whh_h, aH[g][js], 0, 0, 0);
                aH[g][js] = __builtin_amdgcn_mfma_f32_16x16x32_bf16(hhi, whh_l, aH[g][js], 0, 0, 0);
                aH[g][js] = __builtin_amdgcn_mfma_f32_16x16x32_bf16(hlo, whh_h, aH[g][js], 0, 0, 0);
            }
        }
    }

    // ---- gates epilogue ----
#pragma unroll
    for (int js = 0; js < 4; ++js) {
        int j = jg * 64 + js * 16 + l16;
        float biR = bi[j],       bhR = bh[j];
        float biZ = bi[128 + j], bhZ = bh[128 + j];
        float biN = bi[256 + j], bhN = bh[256 + j];
#pragma unroll
        for (int r = 0; r < 4; ++r) {
            int node = n0 + ng * 16 + lq * 4 + r;
            float rv = sigmoidf_(aI[0][js][r] + aH[0][js][r] + biR + bhR);
            float zv = sigmoidf_(aI[1][js][r] + aH[1][js][r] + biZ + bhZ);
            float nv = tanhf_(aI[2][js][r] + biN + rv * (aH[2][js][r] + bhN));
            float hold = hbuf[(long)node * HH + j];
            hout[(long)node * HH + j] = (1.f - zv) * nv + zv * hold;
        }
    }
}

// ============ final copy ws-x -> d_out ============
__global__ __launch_bounds__(256) void k_copy(const float4* __restrict__ s, float4* __restrict__ d)
{
    long i = (long)blockIdx.x * 256 + threadIdx.x;
    d[i] = s[i];
}

extern "C" void kernel_launch(void* const* d_in, const int* in_sizes, int n_in,
                              void* d_out, int out_size, void* d_ws, size_t ws_size,
                              hipStream_t stream)
{
    const float* nf     = (const float*)d_in[0];
    const int*   src    = (const int*)d_in[1];
    const int*   dsti   = (const int*)d_in[2];
    const float* W_init = (const float*)d_in[3];
    const float* lin_W  = (const float*)d_in[4];
    const float* lin_b  = (const float*)d_in[5];
    const float* Wih    = (const float*)d_in[6];
    const float* Whh    = (const float*)d_in[7];
    const float* bih    = (const float*)d_in[8];
    const float* bhh    = (const float*)d_in[9];

    // ws (<=128 MiB, known-safe): h f32 [0,64MiB), x f32 [64,128MiB)
    char* ws = (char*)d_ws;
    float* h   = (float*)ws;
    float* xws = (float*)(ws + (64ull << 20));
    // CSR build scratch inside x region (dead once layers start)
    int* deg    = (int*)(ws + (64ull << 20));
    int* cursor = (int*)(ws + (64ull << 20) + (512 << 10));
    int* bsum   = (int*)(ws + (64ull << 20) + (1 << 20));

    // persistent CSR + split weights live in d_out's head; overwritten by final copy
    char* ob = (char*)d_out;
    int* row_start = (int*)ob;                         // (N+1)*4
    int* csr_src   = (int*)(ob + (1ull << 20));        // 4 MiB
    unsigned short* lWhi  = (unsigned short*)(ob + (6ull << 20));
    unsigned short* lWlo  = lWhi  + 3 * 128 * 128;
    unsigned short* Wihhi = lWlo  + 3 * 128 * 128;
    unsigned short* Wihlo = Wihhi + 3 * 384 * 128;
    unsigned short* Whhhi = Wihlo + 3 * 384 * 128;
    unsigned short* Whhlo = Whhhi + 3 * 384 * 128;

    // init transform
    k_init_gemm<<<NN / 2, 256, 0, stream>>>(nf, W_init, h, NN);

    // CSR build
    hipMemsetAsync(deg, 0, (size_t)NN * 4, stream);
    hipMemsetAsync(cursor, 0, (size_t)NN * 4, stream);
    k_hist<<<EE / 256, 256, 0, stream>>>(dsti, deg);
    k_scan1<<<NN / 1024, 256, 0, stream>>>(deg, bsum);
    k_scan2<<<1, 64, 0, stream>>>(bsum, NN / 1024);
    k_scan3<<<NN / 1024, 256, 0, stream>>>(deg, bsum, row_start);
    k_fill<<<EE / 256, 256, 0, stream>>>(src, dsti, row_start, cursor, csr_src);

    // weight splits
    k_split<<<(3 * 128 * 128 + 255) / 256, 256, 0, stream>>>(lin_W, lWhi, lWlo, 3 * 128 * 128);
    k_split<<<(3 * 384 * 128 + 255) / 256, 256, 0, stream>>>(Wih, Wihhi, Wihlo, 3 * 384 * 128);
    k_split<<<(3 * 384 * 128 + 255) / 256, 256, 0, stream>>>(Whh, Whhhi, Whhlo, 3 * 384 * 128);

    for (int l = 0; l < LL; ++l) {
        k_x<<<NN / 32, 256, 0, stream>>>(
            h, row_start, csr_src,
            lWhi + (long)l * 128 * 128, lWlo + (long)l * 128 * 128,
            lin_b + (long)l * 128, xws);
        float* hout = (l == LL - 1) ? xws : h;   // last layer: write h' over x (safe), then copy out
        k_gru<<<NN / 32, 256, 0, stream>>>(
            xws, h, hout,
            Wihhi + (long)l * 384 * 128, Wihlo + (long)l * 384 * 128,
            Whhhi + (long)l * 384 * 128, Whhlo + (long)l * 384 * 128,
            bih + (long)l * 384, bhh + (long)l * 384);
    }

    k_copy<<<NN * HH / 4 / 256, 256, 0, stream>>>((const float4*)xws, (float4*)d_out);
}

// Round 5
// 1647.406 us; speedup vs baseline: 3.1757x; 1.3636x over previous
//
#include <hip/hip_runtime.h>
#include <hip/hip_bf16.h>

#define NN 131072
#define EE 1048576
#define IN_F 74
#define HH 128
#define LL 3

using f32x4  = __attribute__((ext_vector_type(4))) float;
using f32x16 = __attribute__((ext_vector_type(16))) float;
using bf16x8 = __attribute__((ext_vector_type(8))) short;
typedef unsigned short ushort_t;
typedef unsigned int uint_t;

__device__ __forceinline__ short f2bf(float f) {
    __hip_bfloat16 b = __float2bfloat16(f);
    return __builtin_bit_cast(short, b);
}
__device__ __forceinline__ float bf2f(short s) {
    unsigned int u = ((unsigned int)(unsigned short)s) << 16;
    return __builtin_bit_cast(float, u);
}
__device__ __forceinline__ float bitf(uint_t u) { return __builtin_bit_cast(float, u); }
__device__ __forceinline__ float sigmoidf_(float x) { return 1.f / (1.f + __expf(-x)); }
__device__ __forceinline__ float tanhf_(float x)
{
    x = fminf(fmaxf(x, -15.f), 15.f);
    float e2 = __expf(2.f * x);
    return (e2 - 1.f) / (e2 + 1.f);
}

// ============ init: h = nf @ W_init -> bf16 hi/lo planes ============
__global__ __launch_bounds__(256) void k_init_gemm(
    const float* __restrict__ nf, const float* __restrict__ Wi,
    ushort_t* __restrict__ hhi, ushort_t* __restrict__ hlo)
{
    int node = blockIdx.x * 2 + (threadIdx.x >> 7);
    int c = threadIdx.x & 127;
    const float* row = nf + (long)node * IN_F;
    float s = 0.f;
#pragma unroll
    for (int k = 0; k < IN_F; ++k)
        s += row[k] * Wi[k * HH + c];
    long adr = (long)node * HH + c;
    short hi = f2bf(s);
    hhi[adr] = (ushort_t)hi;
    hlo[adr] = (ushort_t)f2bf(s - bf2f(hi));
}

// ============ CSR build ============
__global__ __launch_bounds__(256) void k_hist(const int* __restrict__ dsti, int* __restrict__ deg)
{
    int e = blockIdx.x * 256 + threadIdx.x;
    atomicAdd(&deg[dsti[e]], 1);
}

__global__ __launch_bounds__(256) void k_scan1(const int* __restrict__ deg, int* __restrict__ bsum)
{
    __shared__ int s[256];
    int b = blockIdx.x, t = threadIdx.x;
    int v = 0;
#pragma unroll
    for (int i = 0; i < 4; ++i) v += deg[b * 1024 + t * 4 + i];
    s[t] = v;
    __syncthreads();
    for (int st = 128; st > 0; st >>= 1) {
        if (t < st) s[t] += s[t + st];
        __syncthreads();
    }
    if (t == 0) bsum[b] = s[0];
}

__global__ void k_scan2(int* __restrict__ bsum, int nb)
{
    if (threadIdx.x == 0) {
        int run = 0;
        for (int i = 0; i < nb; ++i) { int v = bsum[i]; bsum[i] = run; run += v; }
    }
}

__global__ __launch_bounds__(256) void k_scan3(
    const int* __restrict__ deg, const int* __restrict__ bsum, int* __restrict__ row_start)
{
    __shared__ int s[256];
    int b = blockIdx.x, t = threadIdx.x;
    int base = b * 1024 + t * 4;
    int d0 = deg[base], d1 = deg[base + 1], d2 = deg[base + 2], d3 = deg[base + 3];
    int local = d0 + d1 + d2 + d3;
    s[t] = local;
    __syncthreads();
    for (int st = 1; st < 256; st <<= 1) {
        int v = (t >= st) ? s[t - st] : 0;
        __syncthreads();
        s[t] += v;
        __syncthreads();
    }
    int excl = s[t] - local + bsum[b];
    row_start[base] = excl;
    row_start[base + 1] = excl + d0;
    row_start[base + 2] = excl + d0 + d1;
    row_start[base + 3] = excl + d0 + d1 + d2;
    if (b == gridDim.x - 1 && t == 255) row_start[NN] = excl + local;
}

__global__ __launch_bounds__(256) void k_fill(
    const int* __restrict__ src, const int* __restrict__ dsti,
    const int* __restrict__ row_start, int* __restrict__ cursor, int* __restrict__ csr_src)
{
    int e = blockIdx.x * 256 + threadIdx.x;
    int d = dsti[e];
    int pos = atomicAdd(&cursor[d], 1);
    csr_src[row_start[d] + pos] = src[e];
}

// ============ weight split f32 -> (hi, lo) bf16 planes ============
__global__ __launch_bounds__(256) void k_split(
    const float* __restrict__ srcw, ushort_t* __restrict__ hi,
    ushort_t* __restrict__ lo, int n)
{
    int i = blockIdx.x * 256 + threadIdx.x;
    if (i >= n) return;
    float a = srcw[i];
    short h = f2bf(a);
    float rem = a - bf2f(h);
    hi[i] = (ushort_t)h;
    lo[i] = (ushort_t)f2bf(rem);
}

// ============ fused gather + x-GEMM ============
// Block: 32 nodes, 4 waves. Gather reads h hi/lo planes (uint = 2 cols/lane).
// GEMM: 16x16x32 split-bf16 -> x hi/lo planes.
__global__ __launch_bounds__(256) void k_x(
    const ushort_t* __restrict__ hhi, const ushort_t* __restrict__ hlo,
    const int* __restrict__ row_start, const int* __restrict__ csr_src,
    const ushort_t* __restrict__ lWhi, const ushort_t* __restrict__ lWlo,
    const float* __restrict__ lb,
    ushort_t* __restrict__ xhi, ushort_t* __restrict__ xlo)
{
    __shared__ float aggs[32 * 128];
    char* abase = (char*)aggs;
    int n0 = blockIdx.x * 32;
    int t = threadIdx.x;
    int w = t >> 6, lane = t & 63;

    // ---- gather: cols {2*lane, 2*lane+1} per lane ----
    for (int i = 0; i < 8; ++i) {
        int nl = w * 8 + i;
        int node = n0 + nl;
        int e0 = row_start[node], e1 = row_start[node + 1];
        float a0 = 0.f, a1 = 0.f;
        int e = e0;
        for (; e + 1 < e1; e += 2) {
            int s0 = csr_src[e], s1 = csr_src[e + 1];
            uint_t vh0 = *(const uint_t*)(hhi + (long)s0 * HH + lane * 2);
            uint_t vl0 = *(const uint_t*)(hlo + (long)s0 * HH + lane * 2);
            uint_t vh1 = *(const uint_t*)(hhi + (long)s1 * HH + lane * 2);
            uint_t vl1 = *(const uint_t*)(hlo + (long)s1 * HH + lane * 2);
            a0 += bitf(vh0 << 16) + bitf(vl0 << 16);
            a1 += bitf(vh0 & 0xffff0000u) + bitf(vl0 & 0xffff0000u);
            a0 += bitf(vh1 << 16) + bitf(vl1 << 16);
            a1 += bitf(vh1 & 0xffff0000u) + bitf(vl1 & 0xffff0000u);
        }
        if (e < e1) {
            int s0 = csr_src[e];
            uint_t vh0 = *(const uint_t*)(hhi + (long)s0 * HH + lane * 2);
            uint_t vl0 = *(const uint_t*)(hlo + (long)s0 * HH + lane * 2);
            a0 += bitf(vh0 << 16) + bitf(vl0 << 16);
            a1 += bitf(vh0 & 0xffff0000u) + bitf(vl0 & 0xffff0000u);
        }
        int swz = (nl & 7) << 4;
        float2 st = make_float2(a0, a1);
        *reinterpret_cast<float2*>(abase + ((nl * 512 + lane * 8) ^ swz)) = st;
    }
    __syncthreads();

    // ---- GEMM: x = relu(agg @ lW^T + lb) ----
    int ng = w >> 1, jg = w & 1;
    int l16 = lane & 15, lq = lane >> 4;

    f32x4 acc[4];
#pragma unroll
    for (int js = 0; js < 4; ++js) acc[js] = (f32x4){0.f, 0.f, 0.f, 0.f};

#pragma unroll
    for (int kk = 0; kk < 4; ++kk) {
        int k0 = kk * 32;
        int nodeL = ng * 16 + l16;
        int kb = (k0 + lq * 8) * 4;
        int swz = (nodeL & 7) << 4;
        float4 f0 = *reinterpret_cast<const float4*>(abase + ((nodeL * 512 + kb) ^ swz));
        float4 f1 = *reinterpret_cast<const float4*>(abase + ((nodeL * 512 + kb + 16) ^ swz));
        float av[8] = {f0.x, f0.y, f0.z, f0.w, f1.x, f1.y, f1.z, f1.w};
        bf16x8 ahi, alo;
#pragma unroll
        for (int e = 0; e < 8; ++e) {
            short hh_ = f2bf(av[e]);
            ahi[e] = hh_;
            alo[e] = f2bf(av[e] - bf2f(hh_));
        }
#pragma unroll
        for (int js = 0; js < 4; ++js) {
            int jrow = jg * 64 + js * 16 + l16;
            bf16x8 Bh = *reinterpret_cast<const bf16x8*>(lWhi + (long)jrow * HH + k0 + lq * 8);
            bf16x8 Bl = *reinterpret_cast<const bf16x8*>(lWlo + (long)jrow * HH + k0 + lq * 8);
            acc[js] = __builtin_amdgcn_mfma_f32_16x16x32_bf16(ahi, Bh, acc[js], 0, 0, 0);
            acc[js] = __builtin_amdgcn_mfma_f32_16x16x32_bf16(ahi, Bl, acc[js], 0, 0, 0);
            acc[js] = __builtin_amdgcn_mfma_f32_16x16x32_bf16(alo, Bh, acc[js], 0, 0, 0);
        }
    }

#pragma unroll
    for (int js = 0; js < 4; ++js) {
        int j = jg * 64 + js * 16 + l16;
        float bj = lb[j];
#pragma unroll
        for (int r = 0; r < 4; ++r) {
            int node = n0 + ng * 16 + lq * 4 + r;
            float v = fmaxf(acc[js][r] + bj, 0.f);
            long adr = (long)node * HH + j;
            short hi_ = f2bf(v);
            xhi[adr] = (ushort_t)hi_;
            xlo[adr] = (ushort_t)f2bf(v - bf2f(hi_));
        }
    }
}

// ============ fused GRU: 32x32x16 MFMA, rz concat-K, in-place h update ============
// Block: 64 nodes, 4 waves = (ng:2 node-groups x og:2 j-halves).
// Wave: 32 nodes x 64 j x 3 gates.  (round-4 bug: grid covered only half the nodes)
__global__ __launch_bounds__(256, 2) void k_gru(
    const ushort_t* __restrict__ xhi, const ushort_t* __restrict__ xlo,
    ushort_t* __restrict__ hhi, ushort_t* __restrict__ hlo,
    const ushort_t* __restrict__ Wihhi, const ushort_t* __restrict__ Wihlo,
    const ushort_t* __restrict__ Whhhi, const ushort_t* __restrict__ Whhlo,
    const float* __restrict__ bi, const float* __restrict__ bh)
{
    int t = threadIdx.x;
    int w = t >> 6, lane = t & 63;
    int ng = w >> 1, og = w & 1;
    int l31 = lane & 31, lh = lane >> 5;
    int n0 = blockIdx.x * 64;
    long arow = (long)(n0 + ng * 32 + l31) * HH;

    f32x16 aR[2], aZ[2];
#pragma unroll
    for (int js = 0; js < 2; ++js)
#pragma unroll
        for (int i = 0; i < 16; ++i) { aR[js][i] = 0.f; aZ[js][i] = 0.f; }

    // ---- r,z over concat K=256 ([x|h]) ----
#pragma unroll
    for (int half = 0; half < 2; ++half) {
        const ushort_t* Ah = half ? hhi : xhi;
        const ushort_t* Al = half ? hlo : xlo;
        const ushort_t* Bh = half ? Whhhi : Wihhi;
        const ushort_t* Bl = half ? Whhlo : Wihlo;
#pragma unroll
        for (int kc = 0; kc < 8; ++kc) {
            int k = kc * 16 + lh * 8;
            bf16x8 ahi = *reinterpret_cast<const bf16x8*>(Ah + arow + k);
            bf16x8 alo = *reinterpret_cast<const bf16x8*>(Al + arow + k);
#pragma unroll
            for (int js = 0; js < 2; ++js) {
                long rR = (long)(og * 64 + js * 32 + l31) * HH + k;
                long rZ = rR + 128 * HH;
                bf16x8 bRh = *reinterpret_cast<const bf16x8*>(Bh + rR);
                bf16x8 bRl = *reinterpret_cast<const bf16x8*>(Bl + rR);
                bf16x8 bZh = *reinterpret_cast<const bf16x8*>(Bh + rZ);
                bf16x8 bZl = *reinterpret_cast<const bf16x8*>(Bl + rZ);
                aR[js] = __builtin_amdgcn_mfma_f32_32x32x16_bf16(ahi, bRh, aR[js], 0, 0, 0);
                aR[js] = __builtin_amdgcn_mfma_f32_32x32x16_bf16(ahi, bRl, aR[js], 0, 0, 0);
                aR[js] = __builtin_amdgcn_mfma_f32_32x32x16_bf16(alo, bRh, aR[js], 0, 0, 0);
                aZ[js] = __builtin_amdgcn_mfma_f32_32x32x16_bf16(ahi, bZh, aZ[js], 0, 0, 0);
                aZ[js] = __builtin_amdgcn_mfma_f32_32x32x16_bf16(ahi, bZl, aZ[js], 0, 0, 0);
                aZ[js] = __builtin_amdgcn_mfma_f32_32x32x16_bf16(alo, bZh, aZ[js], 0, 0, 0);
            }
        }
    }

    // r,z activations (release aR/aZ)
    float r_[2][16], z_[2][16];
#pragma unroll
    for (int js = 0; js < 2; ++js) {
        int jj = og * 64 + js * 32 + l31;
        float bR = bi[jj] + bh[jj];
        float bZ = bi[128 + jj] + bh[128 + jj];
#pragma unroll
        for (int i = 0; i < 16; ++i) {
            r_[js][i] = sigmoidf_(aR[js][i] + bR);
            z_[js][i] = sigmoidf_(aZ[js][i] + bZ);
        }
    }

    // ---- i_n = x @ Wih_n ----
    f32x16 aNI[2];
#pragma unroll
    for (int js = 0; js < 2; ++js)
#pragma unroll
        for (int i = 0; i < 16; ++i) aNI[js][i] = 0.f;
#pragma unroll
    for (int kc = 0; kc < 8; ++kc) {
        int k = kc * 16 + lh * 8;
        bf16x8 ahi = *reinterpret_cast<const bf16x8*>(xhi + arow + k);
        bf16x8 alo = *reinterpret_cast<const bf16x8*>(xlo + arow + k);
#pragma unroll
        for (int js = 0; js < 2; ++js) {
            long rN = (long)(256 + og * 64 + js * 32 + l31) * HH + k;
            bf16x8 bNh = *reinterpret_cast<const bf16x8*>(Wihhi + rN);
            bf16x8 bNl = *reinterpret_cast<const bf16x8*>(Wihlo + rN);
            aNI[js] = __builtin_amdgcn_mfma_f32_32x32x16_bf16(ahi, bNh, aNI[js], 0, 0, 0);
            aNI[js] = __builtin_amdgcn_mfma_f32_32x32x16_bf16(ahi, bNl, aNI[js], 0, 0, 0);
            aNI[js] = __builtin_amdgcn_mfma_f32_32x32x16_bf16(alo, bNh, aNI[js], 0, 0, 0);
        }
    }

    // ---- h_n = h @ Whh_n ----
    f32x16 aNH[2];
#pragma unroll
    for (int js = 0; js < 2; ++js)
#pragma unroll
        for (int i = 0; i < 16; ++i) aNH[js][i] = 0.f;
#pragma unroll
    for (int kc = 0; kc < 8; ++kc) {
        int k = kc * 16 + lh * 8;
        bf16x8 ahi = *reinterpret_cast<const bf16x8*>(hhi + arow + k);
        bf16x8 alo = *reinterpret_cast<const bf16x8*>(hlo + arow + k);
#pragma unroll
        for (int js = 0; js < 2; ++js) {
            long rN = (long)(256 + og * 64 + js * 32 + l31) * HH + k;
            bf16x8 bNh = *reinterpret_cast<const bf16x8*>(Whhhi + rN);
            bf16x8 bNl = *reinterpret_cast<const bf16x8*>(Whhlo + rN);
            aNH[js] = __builtin_amdgcn_mfma_f32_32x32x16_bf16(ahi, bNh, aNH[js], 0, 0, 0);
            aNH[js] = __builtin_amdgcn_mfma_f32_32x32x16_bf16(ahi, bNl, aNH[js], 0, 0, 0);
            aNH[js] = __builtin_amdgcn_mfma_f32_32x32x16_bf16(alo, bNh, aNH[js], 0, 0, 0);
        }
    }

    // all h-plane reads done; sibling waves may now overwrite their cols
    __syncthreads();

    // ---- gates epilogue, in-place h update ----
#pragma unroll
    for (int js = 0; js < 2; ++js) {
        int jj = og * 64 + js * 32 + l31;
        float bN_i = bi[256 + jj];
        float bN_h = bh[256 + jj];
#pragma unroll
        for (int reg = 0; reg < 16; ++reg) {
            int ndl = ng * 32 + (reg & 3) + 8 * (reg >> 2) + 4 * lh;
            long adr = (long)(n0 + ndl) * HH + jj;
            float hold = bf2f((short)hhi[adr]) + bf2f((short)hlo[adr]);
            float nv = tanhf_(aNI[js][reg] + bN_i + r_[js][reg] * (aNH[js][reg] + bN_h));
            float zv = z_[js][reg];
            float hp = (1.f - zv) * nv + zv * hold;
            short hi_ = f2bf(hp);
            hhi[adr] = (ushort_t)hi_;
            hlo[adr] = (ushort_t)f2bf(hp - bf2f(hi_));
        }
    }
}

// ============ final: d_out = hhi + hlo (f32) ============
__global__ __launch_bounds__(256) void k_copy(
    const uint_t* __restrict__ hhi, const uint_t* __restrict__ hlo,
    float2* __restrict__ out)
{
    long i = (long)blockIdx.x * 256 + threadIdx.x;
    uint_t vh = hhi[i], vl = hlo[i];
    float2 o;
    o.x = bitf(vh << 16) + bitf(vl << 16);
    o.y = bitf(vh & 0xffff0000u) + bitf(vl & 0xffff0000u);
    out[i] = o;
}

extern "C" void kernel_launch(void* const* d_in, const int* in_sizes, int n_in,
                              void* d_out, int out_size, void* d_ws, size_t ws_size,
                              hipStream_t stream)
{
    const float* nf     = (const float*)d_in[0];
    const int*   src    = (const int*)d_in[1];
    const int*   dsti   = (const int*)d_in[2];
    const float* W_init = (const float*)d_in[3];
    const float* lin_W  = (const float*)d_in[4];
    const float* lin_b  = (const float*)d_in[5];
    const float* Wih    = (const float*)d_in[6];
    const float* Whh    = (const float*)d_in[7];
    const float* bih    = (const float*)d_in[8];
    const float* bhh    = (const float*)d_in[9];

    // ws (128 MiB): h planes [0,64), x planes [64,128)
    char* ws = (char*)d_ws;
    ushort_t* hhi = (ushort_t*)ws;
    ushort_t* hlo = (ushort_t*)(ws + (32ull << 20));
    ushort_t* xhi = (ushort_t*)(ws + (64ull << 20));
    ushort_t* xlo = (ushort_t*)(ws + (96ull << 20));
    // CSR build scratch overlaps x region (dead before first k_x)
    int* deg    = (int*)(ws + (64ull << 20));
    int* cursor = (int*)(ws + (64ull << 20) + (1 << 20));
    int* bsum   = (int*)(ws + (64ull << 20) + (2 << 20));

    // persistent CSR + split weights in d_out head (overwritten by k_copy at end)
    char* ob = (char*)d_out;
    int* row_start = (int*)ob;
    int* csr_src   = (int*)(ob + (1ull << 20));
    ushort_t* lWhi  = (ushort_t*)(ob + (6ull << 20));
    ushort_t* lWlo  = lWhi  + 3 * 128 * 128;
    ushort_t* Wihhi = lWlo  + 3 * 128 * 128;
    ushort_t* Wihlo = Wihhi + 3 * 384 * 128;
    ushort_t* Whhhi = Wihlo + 3 * 384 * 128;
    ushort_t* Whhlo = Whhhi + 3 * 384 * 128;

    k_init_gemm<<<NN / 2, 256, 0, stream>>>(nf, W_init, hhi, hlo);

    hipMemsetAsync(deg, 0, (size_t)NN * 4, stream);
    hipMemsetAsync(cursor, 0, (size_t)NN * 4, stream);
    k_hist<<<EE / 256, 256, 0, stream>>>(dsti, deg);
    k_scan1<<<NN / 1024, 256, 0, stream>>>(deg, bsum);
    k_scan2<<<1, 64, 0, stream>>>(bsum, NN / 1024);
    k_scan3<<<NN / 1024, 256, 0, stream>>>(deg, bsum, row_start);
    k_fill<<<EE / 256, 256, 0, stream>>>(src, dsti, row_start, cursor, csr_src);

    k_split<<<(3 * 128 * 128 + 255) / 256, 256, 0, stream>>>(lin_W, lWhi, lWlo, 3 * 128 * 128);
    k_split<<<(3 * 384 * 128 + 255) / 256, 256, 0, stream>>>(Wih, Wihhi, Wihlo, 3 * 384 * 128);
    k_split<<<(3 * 384 * 128 + 255) / 256, 256, 0, stream>>>(Whh, Whhhi, Whhlo, 3 * 384 * 128);

    for (int l = 0; l < LL; ++l) {
        k_x<<<NN / 32, 256, 0, stream>>>(
            hhi, hlo, row_start, csr_src,
            lWhi + (long)l * 128 * 128, lWlo + (long)l * 128 * 128,
            lin_b + (long)l * 128, xhi, xlo);
        k_gru<<<NN / 64, 256, 0, stream>>>(
            xhi, xlo, hhi, hlo,
            Wihhi + (long)l * 384 * 128, Wihlo + (long)l * 384 * 128,
            Whhhi + (long)l * 384 * 128, Whhlo + (long)l * 384 * 128,
            bih + (long)l * 384, bhh + (long)l * 384);
    }

    k_copy<<<NN * HH / 2 / 256, 256, 0, stream>>>((const uint_t*)hhi, (const uint_t*)hlo, (float2*)d_out);
}

// Round 6
// 1379.030 us; speedup vs baseline: 3.7937x; 1.1946x over previous
//
#include <hip/hip_runtime.h>
#include <hip/hip_bf16.h>

#define NN 131072
#define EE 1048576
#define IN_F 74
#define HH 128
#define LL 3

using f32x4  = __attribute__((ext_vector_type(4))) float;
using f32x16 = __attribute__((ext_vector_type(16))) float;
using bf16x8 = __attribute__((ext_vector_type(8))) short;
typedef unsigned short ushort_t;
typedef unsigned int uint_t;

__device__ __forceinline__ short f2bf(float f) {
    __hip_bfloat16 b = __float2bfloat16(f);
    return __builtin_bit_cast(short, b);
}
__device__ __forceinline__ float bf2f(short s) {
    unsigned int u = ((unsigned int)(unsigned short)s) << 16;
    return __builtin_bit_cast(float, u);
}
__device__ __forceinline__ float bitf(uint_t u) { return __builtin_bit_cast(float, u); }
__device__ __forceinline__ float sigmoidf_(float x) { return 1.f / (1.f + __expf(-x)); }
__device__ __forceinline__ float tanhf_(float x)
{
    x = fminf(fmaxf(x, -15.f), 15.f);
    float e2 = __expf(2.f * x);
    return (e2 - 1.f) / (e2 + 1.f);
}

// ============ init: h = nf @ W_init -> bf16 hi/lo planes ============
// Block: 32 nodes, 256 threads. Wi + nf tile staged in LDS; thread = 16 outputs
// (4 float4 col-groups) -> 16 independent FMA chains; packed uint2 plane stores.
__global__ __launch_bounds__(256) void k_init_gemm(
    const float* __restrict__ nf, const float* __restrict__ Wi,
    ushort_t* __restrict__ hhi, ushort_t* __restrict__ hlo)
{
    __shared__ float Wis[IN_F * HH];    // 37888 B
    __shared__ float nfs[32 * IN_F];    // 9472 B
    int b = blockIdx.x;
    int t = threadIdx.x;

    // stage Wi: 9472 f32 = 2368 float4, coalesced
    for (int i = t; i < IN_F * HH / 4; i += 256)
        reinterpret_cast<float4*>(Wis)[i] = reinterpret_cast<const float4*>(Wi)[i];
    // stage nf tile: 32*74 = 2368 f32 = 592 float4, contiguous
    {
        const float4* nf4 = reinterpret_cast<const float4*>(nf + (long)b * 32 * IN_F);
        for (int i = t; i < 32 * IN_F / 4; i += 256)
            reinterpret_cast<float4*>(nfs)[i] = nf4[i];
    }
    __syncthreads();

    int nl = t >> 3;         // 0..31 node within tile
    int c0 = (t & 7) * 4;    // 0..28
    float acc[4][4];
#pragma unroll
    for (int hf = 0; hf < 4; ++hf)
#pragma unroll
        for (int j = 0; j < 4; ++j) acc[hf][j] = 0.f;

    const float* nrow = nfs + nl * IN_F;
#pragma unroll 2
    for (int k = 0; k < IN_F; ++k) {
        float a = nrow[k];
#pragma unroll
        for (int hf = 0; hf < 4; ++hf) {
            float4 wv = *reinterpret_cast<const float4*>(Wis + k * HH + hf * 32 + c0);
            acc[hf][0] += a * wv.x;
            acc[hf][1] += a * wv.y;
            acc[hf][2] += a * wv.z;
            acc[hf][3] += a * wv.w;
        }
    }

    int node = b * 32 + nl;
#pragma unroll
    for (int hf = 0; hf < 4; ++hf) {
        uint_t uh[2], ul[2];
#pragma unroll
        for (int p = 0; p < 2; ++p) {
            float v0 = acc[hf][p * 2], v1 = acc[hf][p * 2 + 1];
            short h0 = f2bf(v0), h1 = f2bf(v1);
            short l0 = f2bf(v0 - bf2f(h0)), l1 = f2bf(v1 - bf2f(h1));
            uh[p] = (uint_t)(ushort_t)h0 | ((uint_t)(ushort_t)h1 << 16);
            ul[p] = (uint_t)(ushort_t)l0 | ((uint_t)(ushort_t)l1 << 16);
        }
        long adr = (long)node * HH + hf * 32 + c0;
        *reinterpret_cast<uint2*>(hhi + adr) = make_uint2(uh[0], uh[1]);
        *reinterpret_cast<uint2*>(hlo + adr) = make_uint2(ul[0], ul[1]);
    }
}

// ============ CSR build ============
__global__ __launch_bounds__(256) void k_hist(const int* __restrict__ dsti, int* __restrict__ deg)
{
    int e = blockIdx.x * 256 + threadIdx.x;
    atomicAdd(&deg[dsti[e]], 1);
}

__global__ __launch_bounds__(256) void k_scan1(const int* __restrict__ deg, int* __restrict__ bsum)
{
    __shared__ int s[256];
    int b = blockIdx.x, t = threadIdx.x;
    int v = 0;
#pragma unroll
    for (int i = 0; i < 4; ++i) v += deg[b * 1024 + t * 4 + i];
    s[t] = v;
    __syncthreads();
    for (int st = 128; st > 0; st >>= 1) {
        if (t < st) s[t] += s[t + st];
        __syncthreads();
    }
    if (t == 0) bsum[b] = s[0];
}

__global__ void k_scan2(int* __restrict__ bsum, int nb)
{
    if (threadIdx.x == 0) {
        int run = 0;
        for (int i = 0; i < nb; ++i) { int v = bsum[i]; bsum[i] = run; run += v; }
    }
}

__global__ __launch_bounds__(256) void k_scan3(
    const int* __restrict__ deg, const int* __restrict__ bsum, int* __restrict__ row_start)
{
    __shared__ int s[256];
    int b = blockIdx.x, t = threadIdx.x;
    int base = b * 1024 + t * 4;
    int d0 = deg[base], d1 = deg[base + 1], d2 = deg[base + 2], d3 = deg[base + 3];
    int local = d0 + d1 + d2 + d3;
    s[t] = local;
    __syncthreads();
    for (int st = 1; st < 256; st <<= 1) {
        int v = (t >= st) ? s[t - st] : 0;
        __syncthreads();
        s[t] += v;
        __syncthreads();
    }
    int excl = s[t] - local + bsum[b];
    row_start[base] = excl;
    row_start[base + 1] = excl + d0;
    row_start[base + 2] = excl + d0 + d1;
    row_start[base + 3] = excl + d0 + d1 + d2;
    if (b == gridDim.x - 1 && t == 255) row_start[NN] = excl + local;
}

__global__ __launch_bounds__(256) void k_fill(
    const int* __restrict__ src, const int* __restrict__ dsti,
    const int* __restrict__ row_start, int* __restrict__ cursor, int* __restrict__ csr_src)
{
    int e = blockIdx.x * 256 + threadIdx.x;
    int d = dsti[e];
    int pos = atomicAdd(&cursor[d], 1);
    csr_src[row_start[d] + pos] = src[e];
}

// ============ weight split f32 -> (hi, lo) bf16 planes ============
__global__ __launch_bounds__(256) void k_split(
    const float* __restrict__ srcw, ushort_t* __restrict__ hi,
    ushort_t* __restrict__ lo, int n)
{
    int i = blockIdx.x * 256 + threadIdx.x;
    if (i >= n) return;
    float a = srcw[i];
    short h = f2bf(a);
    float rem = a - bf2f(h);
    hi[i] = (ushort_t)h;
    lo[i] = (ushort_t)f2bf(rem);
}

// ============ fused gather + x-GEMM ============
// Block: 32 nodes, 4 waves. Gather: 4-deep unrolled edge loop (8 outstanding
// plane loads/lane). GEMM: 16x16x32 split-bf16 -> x hi/lo planes.
__global__ __launch_bounds__(256) void k_x(
    const ushort_t* __restrict__ hhi, const ushort_t* __restrict__ hlo,
    const int* __restrict__ row_start, const int* __restrict__ csr_src,
    const ushort_t* __restrict__ lWhi, const ushort_t* __restrict__ lWlo,
    const float* __restrict__ lb,
    ushort_t* __restrict__ xhi, ushort_t* __restrict__ xlo)
{
    __shared__ float aggs[32 * 128];
    char* abase = (char*)aggs;
    int n0 = blockIdx.x * 32;
    int t = threadIdx.x;
    int w = t >> 6, lane = t & 63;

    // ---- gather: cols {2*lane, 2*lane+1} per lane, unroll-4 over edges ----
    for (int i = 0; i < 8; ++i) {
        int nl = w * 8 + i;
        int node = n0 + nl;
        int e0 = row_start[node], e1 = row_start[node + 1];
        float a0 = 0.f, a1 = 0.f;
        int e = e0;
        for (; e + 3 < e1; e += 4) {
            int s0 = csr_src[e], s1 = csr_src[e + 1];
            int s2 = csr_src[e + 2], s3 = csr_src[e + 3];
            uint_t vh0 = *(const uint_t*)(hhi + (long)s0 * HH + lane * 2);
            uint_t vl0 = *(const uint_t*)(hlo + (long)s0 * HH + lane * 2);
            uint_t vh1 = *(const uint_t*)(hhi + (long)s1 * HH + lane * 2);
            uint_t vl1 = *(const uint_t*)(hlo + (long)s1 * HH + lane * 2);
            uint_t vh2 = *(const uint_t*)(hhi + (long)s2 * HH + lane * 2);
            uint_t vl2 = *(const uint_t*)(hlo + (long)s2 * HH + lane * 2);
            uint_t vh3 = *(const uint_t*)(hhi + (long)s3 * HH + lane * 2);
            uint_t vl3 = *(const uint_t*)(hlo + (long)s3 * HH + lane * 2);
            a0 += bitf(vh0 << 16) + bitf(vl0 << 16);
            a1 += bitf(vh0 & 0xffff0000u) + bitf(vl0 & 0xffff0000u);
            a0 += bitf(vh1 << 16) + bitf(vl1 << 16);
            a1 += bitf(vh1 & 0xffff0000u) + bitf(vl1 & 0xffff0000u);
            a0 += bitf(vh2 << 16) + bitf(vl2 << 16);
            a1 += bitf(vh2 & 0xffff0000u) + bitf(vl2 & 0xffff0000u);
            a0 += bitf(vh3 << 16) + bitf(vl3 << 16);
            a1 += bitf(vh3 & 0xffff0000u) + bitf(vl3 & 0xffff0000u);
        }
        for (; e < e1; ++e) {
            int s0 = csr_src[e];
            uint_t vh0 = *(const uint_t*)(hhi + (long)s0 * HH + lane * 2);
            uint_t vl0 = *(const uint_t*)(hlo + (long)s0 * HH + lane * 2);
            a0 += bitf(vh0 << 16) + bitf(vl0 << 16);
            a1 += bitf(vh0 & 0xffff0000u) + bitf(vl0 & 0xffff0000u);
        }
        int swz = (nl & 7) << 4;
        float2 st = make_float2(a0, a1);
        *reinterpret_cast<float2*>(abase + ((nl * 512 + lane * 8) ^ swz)) = st;
    }
    __syncthreads();

    // ---- GEMM: x = relu(agg @ lW^T + lb) ----
    int ng = w >> 1, jg = w & 1;
    int l16 = lane & 15, lq = lane >> 4;

    f32x4 acc[4];
#pragma unroll
    for (int js = 0; js < 4; ++js) acc[js] = (f32x4){0.f, 0.f, 0.f, 0.f};

#pragma unroll
    for (int kk = 0; kk < 4; ++kk) {
        int k0 = kk * 32;
        int nodeL = ng * 16 + l16;
        int kb = (k0 + lq * 8) * 4;
        int swz = (nodeL & 7) << 4;
        float4 f0 = *reinterpret_cast<const float4*>(abase + ((nodeL * 512 + kb) ^ swz));
        float4 f1 = *reinterpret_cast<const float4*>(abase + ((nodeL * 512 + kb + 16) ^ swz));
        float av[8] = {f0.x, f0.y, f0.z, f0.w, f1.x, f1.y, f1.z, f1.w};
        bf16x8 ahi, alo;
#pragma unroll
        for (int e = 0; e < 8; ++e) {
            short hh_ = f2bf(av[e]);
            ahi[e] = hh_;
            alo[e] = f2bf(av[e] - bf2f(hh_));
        }
#pragma unroll
        for (int js = 0; js < 4; ++js) {
            int jrow = jg * 64 + js * 16 + l16;
            bf16x8 Bh = *reinterpret_cast<const bf16x8*>(lWhi + (long)jrow * HH + k0 + lq * 8);
            bf16x8 Bl = *reinterpret_cast<const bf16x8*>(lWlo + (long)jrow * HH + k0 + lq * 8);
            acc[js] = __builtin_amdgcn_mfma_f32_16x16x32_bf16(ahi, Bh, acc[js], 0, 0, 0);
            acc[js] = __builtin_amdgcn_mfma_f32_16x16x32_bf16(ahi, Bl, acc[js], 0, 0, 0);
            acc[js] = __builtin_amdgcn_mfma_f32_16x16x32_bf16(alo, Bh, acc[js], 0, 0, 0);
        }
    }

#pragma unroll
    for (int js = 0; js < 4; ++js) {
        int j = jg * 64 + js * 16 + l16;
        float bj = lb[j];
#pragma unroll
        for (int r = 0; r < 4; ++r) {
            int node = n0 + ng * 16 + lq * 4 + r;
            float v = fmaxf(acc[js][r] + bj, 0.f);
            long adr = (long)node * HH + j;
            short hi_ = f2bf(v);
            xhi[adr] = (ushort_t)hi_;
            xlo[adr] = (ushort_t)f2bf(v - bf2f(hi_));
        }
    }
}

// ============ fused GRU: 32x32x16 MFMA, rz concat-K, in-place h update ============
// Block: 64 nodes, 4 waves = (ng:2 node-groups x og:2 j-halves).
__global__ __launch_bounds__(256, 2) void k_gru(
    const ushort_t* __restrict__ xhi, const ushort_t* __restrict__ xlo,
    ushort_t* __restrict__ hhi, ushort_t* __restrict__ hlo,
    const ushort_t* __restrict__ Wihhi, const ushort_t* __restrict__ Wihlo,
    const ushort_t* __restrict__ Whhhi, const ushort_t* __restrict__ Whhlo,
    const float* __restrict__ bi, const float* __restrict__ bh)
{
    int t = threadIdx.x;
    int w = t >> 6, lane = t & 63;
    int ng = w >> 1, og = w & 1;
    int l31 = lane & 31, lh = lane >> 5;
    int n0 = blockIdx.x * 64;
    long arow = (long)(n0 + ng * 32 + l31) * HH;

    f32x16 aR[2], aZ[2];
#pragma unroll
    for (int js = 0; js < 2; ++js)
#pragma unroll
        for (int i = 0; i < 16; ++i) { aR[js][i] = 0.f; aZ[js][i] = 0.f; }

    // ---- r,z over concat K=256 ([x|h]) ----
#pragma unroll
    for (int half = 0; half < 2; ++half) {
        const ushort_t* Ah = half ? hhi : xhi;
        const ushort_t* Al = half ? hlo : xlo;
        const ushort_t* Bh = half ? Whhhi : Wihhi;
        const ushort_t* Bl = half ? Whhlo : Wihlo;
#pragma unroll
        for (int kc = 0; kc < 8; ++kc) {
            int k = kc * 16 + lh * 8;
            bf16x8 ahi = *reinterpret_cast<const bf16x8*>(Ah + arow + k);
            bf16x8 alo = *reinterpret_cast<const bf16x8*>(Al + arow + k);
#pragma unroll
            for (int js = 0; js < 2; ++js) {
                long rR = (long)(og * 64 + js * 32 + l31) * HH + k;
                long rZ = rR + 128 * HH;
                bf16x8 bRh = *reinterpret_cast<const bf16x8*>(Bh + rR);
                bf16x8 bRl = *reinterpret_cast<const bf16x8*>(Bl + rR);
                bf16x8 bZh = *reinterpret_cast<const bf16x8*>(Bh + rZ);
                bf16x8 bZl = *reinterpret_cast<const bf16x8*>(Bl + rZ);
                aR[js] = __builtin_amdgcn_mfma_f32_32x32x16_bf16(ahi, bRh, aR[js], 0, 0, 0);
                aR[js] = __builtin_amdgcn_mfma_f32_32x32x16_bf16(ahi, bRl, aR[js], 0, 0, 0);
                aR[js] = __builtin_amdgcn_mfma_f32_32x32x16_bf16(alo, bRh, aR[js], 0, 0, 0);
                aZ[js] = __builtin_amdgcn_mfma_f32_32x32x16_bf16(ahi, bZh, aZ[js], 0, 0, 0);
                aZ[js] = __builtin_amdgcn_mfma_f32_32x32x16_bf16(ahi, bZl, aZ[js], 0, 0, 0);
                aZ[js] = __builtin_amdgcn_mfma_f32_32x32x16_bf16(alo, bZh, aZ[js], 0, 0, 0);
            }
        }
    }

    // r,z activations (release aR/aZ)
    float r_[2][16], z_[2][16];
#pragma unroll
    for (int js = 0; js < 2; ++js) {
        int jj = og * 64 + js * 32 + l31;
        float bR = bi[jj] + bh[jj];
        float bZ = bi[128 + jj] + bh[128 + jj];
#pragma unroll
        for (int i = 0; i < 16; ++i) {
            r_[js][i] = sigmoidf_(aR[js][i] + bR);
            z_[js][i] = sigmoidf_(aZ[js][i] + bZ);
        }
    }

    // ---- i_n = x @ Wih_n ----
    f32x16 aNI[2];
#pragma unroll
    for (int js = 0; js < 2; ++js)
#pragma unroll
        for (int i = 0; i < 16; ++i) aNI[js][i] = 0.f;
#pragma unroll
    for (int kc = 0; kc < 8; ++kc) {
        int k = kc * 16 + lh * 8;
        bf16x8 ahi = *reinterpret_cast<const bf16x8*>(xhi + arow + k);
        bf16x8 alo = *reinterpret_cast<const bf16x8*>(xlo + arow + k);
#pragma unroll
        for (int js = 0; js < 2; ++js) {
            long rN = (long)(256 + og * 64 + js * 32 + l31) * HH + k;
            bf16x8 bNh = *reinterpret_cast<const bf16x8*>(Wihhi + rN);
            bf16x8 bNl = *reinterpret_cast<const bf16x8*>(Wihlo + rN);
            aNI[js] = __builtin_amdgcn_mfma_f32_32x32x16_bf16(ahi, bNh, aNI[js], 0, 0, 0);
            aNI[js] = __builtin_amdgcn_mfma_f32_32x32x16_bf16(ahi, bNl, aNI[js], 0, 0, 0);
            aNI[js] = __builtin_amdgcn_mfma_f32_32x32x16_bf16(alo, bNh, aNI[js], 0, 0, 0);
        }
    }

    // ---- h_n = h @ Whh_n ----
    f32x16 aNH[2];
#pragma unroll
    for (int js = 0; js < 2; ++js)
#pragma unroll
        for (int i = 0; i < 16; ++i) aNH[js][i] = 0.f;
#pragma unroll
    for (int kc = 0; kc < 8; ++kc) {
        int k = kc * 16 + lh * 8;
        bf16x8 ahi = *reinterpret_cast<const bf16x8*>(hhi + arow + k);
        bf16x8 alo = *reinterpret_cast<const bf16x8*>(hlo + arow + k);
#pragma unroll
        for (int js = 0; js < 2; ++js) {
            long rN = (long)(256 + og * 64 + js * 32 + l31) * HH + k;
            bf16x8 bNh = *reinterpret_cast<const bf16x8*>(Whhhi + rN);
            bf16x8 bNl = *reinterpret_cast<const bf16x8*>(Whhlo + rN);
            aNH[js] = __builtin_amdgcn_mfma_f32_32x32x16_bf16(ahi, bNh, aNH[js], 0, 0, 0);
            aNH[js] = __builtin_amdgcn_mfma_f32_32x32x16_bf16(ahi, bNl, aNH[js], 0, 0, 0);
            aNH[js] = __builtin_amdgcn_mfma_f32_32x32x16_bf16(alo, bNh, aNH[js], 0, 0, 0);
        }
    }

    // all h-plane reads done; sibling waves may now overwrite their cols
    __syncthreads();

    // ---- gates epilogue, in-place h update ----
#pragma unroll
    for (int js = 0; js < 2; ++js) {
        int jj = og * 64 + js * 32 + l31;
        float bN_i = bi[256 + jj];
        float bN_h = bh[256 + jj];
#pragma unroll
        for (int reg = 0; reg < 16; ++reg) {
            int ndl = ng * 32 + (reg & 3) + 8 * (reg >> 2) + 4 * lh;
            long adr = (long)(n0 + ndl) * HH + jj;
            float hold = bf2f((short)hhi[adr]) + bf2f((short)hlo[adr]);
            float nv = tanhf_(aNI[js][reg] + bN_i + r_[js][reg] * (aNH[js][reg] + bN_h));
            float zv = z_[js][reg];
            float hp = (1.f - zv) * nv + zv * hold;
            short hi_ = f2bf(hp);
            hhi[adr] = (ushort_t)hi_;
            hlo[adr] = (ushort_t)f2bf(hp - bf2f(hi_));
        }
    }
}

// ============ final: d_out = hhi + hlo (f32) ============
__global__ __launch_bounds__(256) void k_copy(
    const uint_t* __restrict__ hhi, const uint_t* __restrict__ hlo,
    float2* __restrict__ out)
{
    long i = (long)blockIdx.x * 256 + threadIdx.x;
    uint_t vh = hhi[i], vl = hlo[i];
    float2 o;
    o.x = bitf(vh << 16) + bitf(vl << 16);
    o.y = bitf(vh & 0xffff0000u) + bitf(vl & 0xffff0000u);
    out[i] = o;
}

extern "C" void kernel_launch(void* const* d_in, const int* in_sizes, int n_in,
                              void* d_out, int out_size, void* d_ws, size_t ws_size,
                              hipStream_t stream)
{
    const float* nf     = (const float*)d_in[0];
    const int*   src    = (const int*)d_in[1];
    const int*   dsti   = (const int*)d_in[2];
    const float* W_init = (const float*)d_in[3];
    const float* lin_W  = (const float*)d_in[4];
    const float* lin_b  = (const float*)d_in[5];
    const float* Wih    = (const float*)d_in[6];
    const float* Whh    = (const float*)d_in[7];
    const float* bih    = (const float*)d_in[8];
    const float* bhh    = (const float*)d_in[9];

    // ws (128 MiB): h planes [0,64), x planes [64,128)
    char* ws = (char*)d_ws;
    ushort_t* hhi = (ushort_t*)ws;
    ushort_t* hlo = (ushort_t*)(ws + (32ull << 20));
    ushort_t* xhi = (ushort_t*)(ws + (64ull << 20));
    ushort_t* xlo = (ushort_t*)(ws + (96ull << 20));
    // CSR build scratch overlaps x region (dead before first k_x)
    int* deg    = (int*)(ws + (64ull << 20));
    int* cursor = (int*)(ws + (64ull << 20) + (1 << 20));
    int* bsum   = (int*)(ws + (64ull << 20) + (2 << 20));

    // persistent CSR + split weights in d_out head (overwritten by k_copy at end)
    char* ob = (char*)d_out;
    int* row_start = (int*)ob;
    int* csr_src   = (int*)(ob + (1ull << 20));
    ushort_t* lWhi  = (ushort_t*)(ob + (6ull << 20));
    ushort_t* lWlo  = lWhi  + 3 * 128 * 128;
    ushort_t* Wihhi = lWlo  + 3 * 128 * 128;
    ushort_t* Wihlo = Wihhi + 3 * 384 * 128;
    ushort_t* Whhhi = Wihlo + 3 * 384 * 128;
    ushort_t* Whhlo = Whhhi + 3 * 384 * 128;

    k_init_gemm<<<NN / 32, 256, 0, stream>>>(nf, W_init, hhi, hlo);

    hipMemsetAsync(deg, 0, (size_t)NN * 4, stream);
    hipMemsetAsync(cursor, 0, (size_t)NN * 4, stream);
    k_hist<<<EE / 256, 256, 0, stream>>>(dsti, deg);
    k_scan1<<<NN / 1024, 256, 0, stream>>>(deg, bsum);
    k_scan2<<<1, 64, 0, stream>>>(bsum, NN / 1024);
    k_scan3<<<NN / 1024, 256, 0, stream>>>(deg, bsum, row_start);
    k_fill<<<EE / 256, 256, 0, stream>>>(src, dsti, row_start, cursor, csr_src);

    k_split<<<(3 * 128 * 128 + 255) / 256, 256, 0, stream>>>(lin_W, lWhi, lWlo, 3 * 128 * 128);
    k_split<<<(3 * 384 * 128 + 255) / 256, 256, 0, stream>>>(Wih, Wihhi, Wihlo, 3 * 384 * 128);
    k_split<<<(3 * 384 * 128 + 255) / 256, 256, 0, stream>>>(Whh, Whhhi, Whhlo, 3 * 384 * 128);

    for (int l = 0; l < LL; ++l) {
        k_x<<<NN / 32, 256, 0, stream>>>(
            hhi, hlo, row_start, csr_src,
            lWhi + (long)l * 128 * 128, lWlo + (long)l * 128 * 128,
            lin_b + (long)l * 128, xhi, xlo);
        k_gru<<<NN / 64, 256, 0, stream>>>(
            xhi, xlo, hhi, hlo,
            Wihhi + (long)l * 384 * 128, Wihlo + (long)l * 384 * 128,
            Whhhi + (long)l * 384 * 128, Whhlo + (long)l * 384 * 128,
            bih + (long)l * 384, bhh + (long)l * 384);
    }

    k_copy<<<NN * HH / 2 / 256, 256, 0, stream>>>((const uint_t*)hhi, (const uint_t*)hlo, (float2*)d_out);
}